// Round 3
// baseline (628.725 us; speedup 1.0000x reference)
//
#include <hip/hip_runtime.h>

// GumbelCodebook: y = one_hot(argmax(logits+gumbel)), z = codebook[argmax]
// Forward value of straight-through estimator collapses to the hard one-hot
// (exact in IEEE except 1 +/- 1ulp at the argmax slot).
//
// R3: wave-per-token structure kept, but (a) 2 tokens per wave interleaved
// for ILP, (b) all 32 float4 loads issued into explicit register arrays
// before consumption (forces deep MLP instead of the 40-VGPR batched dribble
// rocprof showed in R2), (c) non-temporal stores for the 288 MB write-once
// output stream.

#define NUM_CODES 2048
#define CODE_DIM  256
#define BLOCK     256
#define WPB       4      // waves per block
#define VECS      8      // float4 vecs per lane per token: 2048/4/64

typedef float vfloat4 __attribute__((ext_vector_type(4)));

__global__ __launch_bounds__(BLOCK) void gumbel_codebook_kernel(
    const float* __restrict__ logits,
    const float* __restrict__ gumbel,
    const float* __restrict__ codebook,
    float* __restrict__ z_out,   // [tokens, CODE_DIM]
    float* __restrict__ y_out)   // [tokens, NUM_CODES]
{
    const int lane = threadIdx.x & 63;
    const int wid  = blockIdx.x * WPB + (threadIdx.x >> 6);
    const int t0   = wid * 2;
    const int t1   = t0 + 1;

    const float4* l0 = (const float4*)(logits + (size_t)t0 * NUM_CODES);
    const float4* g0 = (const float4*)(gumbel + (size_t)t0 * NUM_CODES);
    const float4* l1 = (const float4*)(logits + (size_t)t1 * NUM_CODES);
    const float4* g1 = (const float4*)(gumbel + (size_t)t1 * NUM_CODES);

    // Issue ALL 32 global_load_dwordx4 before any consumption.
    float4 L0[VECS], G0[VECS], L1[VECS], G1[VECS];
#pragma unroll
    for (int i = 0; i < VECS; ++i) L0[i] = l0[lane + 64 * i];
#pragma unroll
    for (int i = 0; i < VECS; ++i) G0[i] = g0[lane + 64 * i];
#pragma unroll
    for (int i = 0; i < VECS; ++i) L1[i] = l1[lane + 64 * i];
#pragma unroll
    for (int i = 0; i < VECS; ++i) G1[i] = g1[lane + 64 * i];

    // Per-lane argmax, two independent chains. Increasing base order +
    // strict '>' keeps first occurrence (jnp.argmax tie-break).
    float b0 = -INFINITY, b1 = -INFINITY;
    int   i0 = NUM_CODES,  i1 = NUM_CODES;
#pragma unroll
    for (int i = 0; i < VECS; ++i) {
        const int base = (lane + 64 * i) * 4;
        float s;
        s = L0[i].x + G0[i].x; if (s > b0) { b0 = s; i0 = base + 0; }
        s = L0[i].y + G0[i].y; if (s > b0) { b0 = s; i0 = base + 1; }
        s = L0[i].z + G0[i].z; if (s > b0) { b0 = s; i0 = base + 2; }
        s = L0[i].w + G0[i].w; if (s > b0) { b0 = s; i0 = base + 3; }
        s = L1[i].x + G1[i].x; if (s > b1) { b1 = s; i1 = base + 0; }
        s = L1[i].y + G1[i].y; if (s > b1) { b1 = s; i1 = base + 1; }
        s = L1[i].z + G1[i].z; if (s > b1) { b1 = s; i1 = base + 2; }
        s = L1[i].w + G1[i].w; if (s > b1) { b1 = s; i1 = base + 3; }
    }

    // 64-lane butterfly argmax, two chains interleaved (DS latency overlap);
    // lower index wins ties.
#pragma unroll
    for (int m = 32; m >= 1; m >>= 1) {
        float ob0 = __shfl_xor(b0, m, 64);
        int   oi0 = __shfl_xor(i0, m, 64);
        float ob1 = __shfl_xor(b1, m, 64);
        int   oi1 = __shfl_xor(i1, m, 64);
        if (ob0 > b0 || (ob0 == b0 && oi0 < i0)) { b0 = ob0; i0 = oi0; }
        if (ob1 > b1 || (ob1 == b1 && oi1 < i1)) { b1 = ob1; i1 = oi1; }
    }

    const int v0 = i0 >> 2, e0 = i0 & 3;
    const int v1 = i1 >> 2, e1 = i1 & 3;

    // y one-hot rows: 8 coalesced non-temporal float4 stores per lane/token.
    vfloat4* y0 = (vfloat4*)(y_out + (size_t)t0 * NUM_CODES);
    vfloat4* y1 = (vfloat4*)(y_out + (size_t)t1 * NUM_CODES);
#pragma unroll
    for (int i = 0; i < VECS; ++i) {
        const int vec = lane + 64 * i;
        vfloat4 o0 = {0.f, 0.f, 0.f, 0.f};
        vfloat4 o1 = {0.f, 0.f, 0.f, 0.f};
        if (vec == v0) o0[e0] = 1.0f;
        if (vec == v1) o1[e1] = 1.0f;
        __builtin_nontemporal_store(o0, &y0[vec]);
        __builtin_nontemporal_store(o1, &y1[vec]);
    }

    // z rows: 64 lanes x float4 = 256 floats; codebook stays cached (regular
    // load), z written once (non-temporal store).
    const vfloat4* c0 = (const vfloat4*)(codebook + (size_t)i0 * CODE_DIM);
    const vfloat4* c1 = (const vfloat4*)(codebook + (size_t)i1 * CODE_DIM);
    vfloat4* z0 = (vfloat4*)(z_out + (size_t)t0 * CODE_DIM);
    vfloat4* z1 = (vfloat4*)(z_out + (size_t)t1 * CODE_DIM);
    __builtin_nontemporal_store(c0[lane], &z0[lane]);
    __builtin_nontemporal_store(c1[lane], &z1[lane]);
}

extern "C" void kernel_launch(void* const* d_in, const int* in_sizes, int n_in,
                              void* d_out, int out_size, void* d_ws, size_t ws_size,
                              hipStream_t stream) {
    const float* logits   = (const float*)d_in[0];
    const float* gumbel   = (const float*)d_in[1];
    const float* codebook = (const float*)d_in[2];

    const int tokens = in_sizes[0] / NUM_CODES;   // 8*4096 = 32768

    float* z_out = (float*)d_out;                              // [tokens, 256]
    float* y_out = (float*)d_out + (size_t)tokens * CODE_DIM;  // [tokens, 2048]

    const int waves  = tokens / 2;          // 2 tokens per wave
    const int blocks = waves / WPB;         // 4096

    gumbel_codebook_kernel<<<blocks, BLOCK, 0, stream>>>(
        logits, gumbel, codebook, z_out, y_out);
}